// Round 1
// baseline (170.014 us; speedup 1.0000x reference)
//
#include <hip/hip_runtime.h>
#include <hip/hip_bf16.h>

#define DD 128
#define NEGS 0.01f

// ---------------- GEMM: z[i][j] = sum_k h[i][k] * W[j][k] ----------------
// 64 rows per block, 256 threads, each thread computes 8 rows x 4 cols.
// Ws[c][k] pad +1 -> bank (c+k)%32; cols mapped tx+32j -> conflict-free.
__global__ __launch_bounds__(256)
void k_gemm(const float* __restrict__ h, const float* __restrict__ W,
            float* __restrict__ z, int N)
{
    __shared__ float Ws[DD][DD + 1];      // 66 KB
    __shared__ float hs[64][DD + 1];      // 33 KB
    const int tid = threadIdx.x;
    for (int i = tid; i < DD * DD; i += 256)
        Ws[i >> 7][i & 127] = W[i];
    const int row0 = blockIdx.x * 64;
    for (int i = tid; i < 64 * DD; i += 256) {
        int r = i >> 7, c = i & 127;
        int gr = row0 + r;
        hs[r][c] = (gr < N) ? h[(size_t)gr * DD + c] : 0.f;
    }
    __syncthreads();
    const int tx = tid & 31;   // column base: cols tx + 32*j
    const int ty = tid >> 5;   // 0..7 -> rows 8*ty .. 8*ty+7
    float acc[8][4];
#pragma unroll
    for (int i = 0; i < 8; ++i)
#pragma unroll
        for (int j = 0; j < 4; ++j) acc[i][j] = 0.f;

    for (int k = 0; k < DD; ++k) {
        float b0 = Ws[tx][k];
        float b1 = Ws[tx + 32][k];
        float b2 = Ws[tx + 64][k];
        float b3 = Ws[tx + 96][k];
#pragma unroll
        for (int i = 0; i < 8; ++i) {
            float a = hs[ty * 8 + i][k];
            acc[i][0] = fmaf(a, b0, acc[i][0]);
            acc[i][1] = fmaf(a, b1, acc[i][1]);
            acc[i][2] = fmaf(a, b2, acc[i][2]);
            acc[i][3] = fmaf(a, b3, acc[i][3]);
        }
    }
#pragma unroll
    for (int i = 0; i < 8; ++i) {
        int gr = row0 + ty * 8 + i;
        if (gr < N) {
            float* zr = z + (size_t)gr * DD;
            zr[tx]      = acc[i][0];
            zr[tx + 32] = acc[i][1];
            zr[tx + 64] = acc[i][2];
            zr[tx + 96] = acc[i][3];
        }
    }
}

// ---------------- logits: ll[i] = z[i,:].a_l  lr[i] = z[i,:].a_r ----------
// one wave per node, lane l handles elements 2l, 2l+1 (coalesced 512B row)
__global__ __launch_bounds__(256)
void k_logits(const float* __restrict__ z, const float* __restrict__ attn,
              float* __restrict__ ll, float* __restrict__ lr, int N)
{
    int wid  = (blockIdx.x * 256 + threadIdx.x) >> 6;
    int lane = threadIdx.x & 63;
    if (wid >= N) return;
    const float2* zrow = (const float2*)(z + (size_t)wid * DD);
    float2 zv = zrow[lane];
    float2 al = ((const float2*)attn)[lane];
    float2 ar = ((const float2*)(attn + DD))[lane];
    float pl = zv.x * al.x + zv.y * al.y;
    float pr = zv.x * ar.x + zv.y * ar.y;
#pragma unroll
    for (int o = 32; o >= 1; o >>= 1) {
        pl += __shfl_xor(pl, o);
        pr += __shfl_xor(pr, o);
    }
    if (lane == 0) { ll[wid] = pl; lr[wid] = pr; }
}

// ---------------- segment starts: start[n] = lower_bound(dst, n) ----------
__global__ __launch_bounds__(256)
void k_starts(const int* __restrict__ dst, int E, int N, int* __restrict__ start)
{
    int n = blockIdx.x * 256 + threadIdx.x;
    if (n > N) return;
    int lo = 0, hi = E;
    while (lo < hi) {
        int mid = (lo + hi) >> 1;
        if (dst[mid] < n) lo = mid + 1; else hi = mid;
    }
    start[n] = lo;
}

// ---------------- edge phase: one wave per destination node --------------
// pass A: wave-parallel segment max of e = leaky(ll[src]+lr[n])
// pass B: per-lane ex = exp(e-m); unnormalized acc += ex * z[src]; divide once.
__global__ __launch_bounds__(256)
void k_edge(const float* __restrict__ z, const int* __restrict__ src,
            const int* __restrict__ start, const float* __restrict__ ll,
            const float* __restrict__ lr, float* __restrict__ out, int N)
{
    int wid  = (blockIdx.x * 256 + threadIdx.x) >> 6;
    int lane = threadIdx.x & 63;
    if (wid >= N) return;
    int s0 = start[wid], s1 = start[wid + 1];
    float2* orow = (float2*)(out + (size_t)wid * DD);
    if (s0 == s1) {                       // empty segment -> zeros
        orow[lane] = make_float2(0.f, 0.f);
        return;
    }
    float lrn = lr[wid];

    // pass A: segment max
    float m = -1e38f;
    for (int base = s0; base < s1; base += 64) {
        int j = base + lane;
        if (j < s1) {
            float v = ll[src[j]] + lrn;
            float e = (v >= 0.f) ? v : NEGS * v;
            m = fmaxf(m, e);
        }
    }
#pragma unroll
    for (int o = 32; o >= 1; o >>= 1) m = fmaxf(m, __shfl_xor(m, o));

    // pass B: exp-sum + unnormalized weighted accumulation
    float ssum = 0.f;
    float2 acc = make_float2(0.f, 0.f);
    for (int base = s0; base < s1; base += 64) {
        int j = base + lane;
        float ex = 0.f;
        int sj = 0;
        if (j < s1) {
            sj = src[j];
            float v = ll[sj] + lrn;
            float e = (v >= 0.f) ? v : NEGS * v;
            ex = __expf(e - m);
        }
        ssum += ex;
        int cnt = min(64, s1 - base);
        for (int t = 0; t < cnt; ++t) {
            float a  = __shfl(ex, t);
            int srcj = __shfl(sj, t);
            float2 zv = ((const float2*)(z + (size_t)srcj * DD))[lane];
            acc.x = fmaf(a, zv.x, acc.x);
            acc.y = fmaf(a, zv.y, acc.y);
        }
    }
#pragma unroll
    for (int o = 32; o >= 1; o >>= 1) ssum += __shfl_xor(ssum, o);
    float inv = 1.0f / ssum;
    orow[lane] = make_float2(acc.x * inv, acc.y * inv);
}

extern "C" void kernel_launch(void* const* d_in, const int* in_sizes, int n_in,
                              void* d_out, int out_size, void* d_ws, size_t ws_size,
                              hipStream_t stream) {
    const float* h    = (const float*)d_in[0];
    const int*   src  = (const int*)d_in[1];
    const int*   dst  = (const int*)d_in[2];
    const float* W    = (const float*)d_in[3];
    const float* attn = (const float*)d_in[4];
    const int N = in_sizes[0] / DD;
    const int E = in_sizes[1];
    float* out = (float*)d_out;

    // workspace layout
    float* z  = (float*)d_ws;                  // N*128 floats (25.6 MB)
    float* ll = z + (size_t)N * DD;            // N floats
    float* lr = ll + N;                        // N floats
    int* start = (int*)(lr + N);               // N+1 ints

    k_gemm<<<(N + 63) / 64, 256, 0, stream>>>(h, W, z, N);
    k_logits<<<(N + 3) / 4, 256, 0, stream>>>(z, attn, ll, lr, N);
    k_starts<<<(N + 1 + 255) / 256, 256, 0, stream>>>(dst, E, N, start);
    k_edge<<<(N + 3) / 4, 256, 0, stream>>>(z, src, start, ll, lr, out, N);
}

// Round 2
// 97.171 us; speedup vs baseline: 1.7496x; 1.7496x over previous
//
#include <hip/hip_runtime.h>
#include <hip/hip_bf16.h>

#define DD 128
#define NEGS 0.01f

typedef float  f32x4 __attribute__((ext_vector_type(4)));
typedef __bf16 bf16x8 __attribute__((ext_vector_type(8)));
typedef unsigned short us8 __attribute__((ext_vector_type(8)));

__device__ __forceinline__ unsigned short f2bf(float f) {
    unsigned int u = __builtin_bit_cast(unsigned int, f);
    u += 0x7FFFu + ((u >> 16) & 1u);          // RNE (no NaN inputs here)
    return (unsigned short)(u >> 16);
}
__device__ __forceinline__ float bf2f(unsigned short s) {
    unsigned int u = ((unsigned int)s) << 16;
    return __builtin_bit_cast(float, u);
}

// ---------- fused GEMM + logits: z16 = bf16(h @ W^T), ll/lr = z @ a_{l,r} ----
// One wave computes 32 full rows of z (2 row-tiles x 8 col-tiles, K=128).
// A frag: lane holds h[i0 + rt*16 + (lane&15)][kk + (lane>>4)*8 .. +8]
// B frag: lane holds W[jt*16 + (lane&15)][kk + (lane>>4)*8 .. +8]   (W is B^T)
// C/D:    col = lane&15, row = (lane>>4)*4 + reg   [verified m89 mapping]
__global__ __launch_bounds__(256)
void k_gemm_mfma(const float* __restrict__ h, const float* __restrict__ W,
                 const float* __restrict__ attn,
                 unsigned short* __restrict__ z16,
                 float* __restrict__ ll, float* __restrict__ lr, int N)
{
    const int lane = threadIdx.x & 63;
    const int gw   = (blockIdx.x * 256 + threadIdx.x) >> 6;
    const int i0   = gw * 32;
    if (i0 >= N) return;
    const int hl = lane & 15;
    const int g  = lane >> 4;
    const int ko = g * 8;

    int r0 = i0 + hl;       if (r0 > N - 1) r0 = N - 1;   // clamp loads; stores guarded
    int r1 = i0 + 16 + hl;  if (r1 > N - 1) r1 = N - 1;

    f32x4 acc[2][8];
#pragma unroll
    for (int rt = 0; rt < 2; ++rt)
#pragma unroll
        for (int jt = 0; jt < 8; ++jt) acc[rt][jt] = f32x4{0.f, 0.f, 0.f, 0.f};

#pragma unroll
    for (int kk = 0; kk < DD; kk += 32) {
        const float* pa0 = h + (size_t)r0 * DD + kk + ko;
        const float* pa1 = h + (size_t)r1 * DD + kk + ko;
        float4 v0a = *(const float4*)pa0, v0b = *(const float4*)(pa0 + 4);
        float4 v1a = *(const float4*)pa1, v1b = *(const float4*)(pa1 + 4);
        us8 ua0 = { f2bf(v0a.x), f2bf(v0a.y), f2bf(v0a.z), f2bf(v0a.w),
                    f2bf(v0b.x), f2bf(v0b.y), f2bf(v0b.z), f2bf(v0b.w) };
        us8 ua1 = { f2bf(v1a.x), f2bf(v1a.y), f2bf(v1a.z), f2bf(v1a.w),
                    f2bf(v1b.x), f2bf(v1b.y), f2bf(v1b.z), f2bf(v1b.w) };
        bf16x8 a0 = __builtin_bit_cast(bf16x8, ua0);
        bf16x8 a1 = __builtin_bit_cast(bf16x8, ua1);
#pragma unroll
        for (int jt = 0; jt < 8; ++jt) {
            const float* pb = W + (size_t)(jt * 16 + hl) * DD + kk + ko;
            float4 wa = *(const float4*)pb, wb = *(const float4*)(pb + 4);
            us8 ub = { f2bf(wa.x), f2bf(wa.y), f2bf(wa.z), f2bf(wa.w),
                       f2bf(wb.x), f2bf(wb.y), f2bf(wb.z), f2bf(wb.w) };
            bf16x8 b = __builtin_bit_cast(bf16x8, ub);
            acc[0][jt] = __builtin_amdgcn_mfma_f32_16x16x32_bf16(a0, b, acc[0][jt], 0, 0, 0);
            acc[1][jt] = __builtin_amdgcn_mfma_f32_16x16x32_bf16(a1, b, acc[1][jt], 0, 0, 0);
        }
    }

    // epilogue: store z16 + fused logits
    float aLc[8], aRc[8];
#pragma unroll
    for (int jt = 0; jt < 8; ++jt) {
        aLc[jt] = attn[jt * 16 + hl];
        aRc[jt] = attn[DD + jt * 16 + hl];
    }
#pragma unroll
    for (int rt = 0; rt < 2; ++rt) {
#pragma unroll
        for (int reg = 0; reg < 4; ++reg) {
            const int row = i0 + rt * 16 + g * 4 + reg;
            float pl = 0.f, pr = 0.f;
#pragma unroll
            for (int jt = 0; jt < 8; ++jt) {
                float v = acc[rt][jt][reg];
                pl = fmaf(v, aLc[jt], pl);
                pr = fmaf(v, aRc[jt], pr);
            }
#pragma unroll
            for (int o = 8; o >= 1; o >>= 1) {   // reduce across the 16 cols
                pl += __shfl_xor(pl, o);
                pr += __shfl_xor(pr, o);
            }
            if (row < N) {
                if (hl == 0) { ll[row] = pl; lr[row] = pr; }
                unsigned short* zr = z16 + (size_t)row * DD;
#pragma unroll
                for (int jt = 0; jt < 8; ++jt)
                    zr[jt * 16 + hl] = f2bf(acc[rt][jt][reg]);
            }
        }
    }
}

// ---------------- segment starts: start[n] = lower_bound(dst, n) ----------
__global__ __launch_bounds__(256)
void k_starts(const int* __restrict__ dst, int E, int N, int* __restrict__ start)
{
    int n = blockIdx.x * 256 + threadIdx.x;
    if (n > N) return;
    int lo = 0, hi = E;
    while (lo < hi) {
        int mid = (lo + hi) >> 1;
        if (dst[mid] < n) lo = mid + 1; else hi = mid;
    }
    start[n] = lo;
}

// ---------------- edge phase: one wave per destination node --------------
__global__ __launch_bounds__(256)
void k_edge(const unsigned short* __restrict__ z16, const int* __restrict__ src,
            const int* __restrict__ start, const float* __restrict__ ll,
            const float* __restrict__ lr, float* __restrict__ out, int N)
{
    int wid  = (blockIdx.x * 256 + threadIdx.x) >> 6;
    int lane = threadIdx.x & 63;
    if (wid >= N) return;
    int s0 = start[wid], s1 = start[wid + 1];
    float2* orow = (float2*)(out + (size_t)wid * DD);
    if (s0 == s1) { orow[lane] = make_float2(0.f, 0.f); return; }
    float lrn = lr[wid];

    // pass A: segment max
    float m = -1e38f;
    for (int base = s0; base < s1; base += 64) {
        int j = base + lane;
        if (j < s1) {
            float v = ll[src[j]] + lrn;
            float e = (v >= 0.f) ? v : NEGS * v;
            m = fmaxf(m, e);
        }
    }
#pragma unroll
    for (int o = 32; o >= 1; o >>= 1) m = fmaxf(m, __shfl_xor(m, o));

    // pass B: exp-sum + unnormalized weighted accumulation (bf16 z gather)
    float ssum = 0.f;
    float2 acc = make_float2(0.f, 0.f);
    for (int base = s0; base < s1; base += 64) {
        int j = base + lane;
        float ex = 0.f; int sj = 0;
        if (j < s1) {
            sj = src[j];
            float v = ll[sj] + lrn;
            float e = (v >= 0.f) ? v : NEGS * v;
            ex = __expf(e - m);
        }
        ssum += ex;
        int cnt = min(64, s1 - base);
        for (int t = 0; t < cnt; ++t) {
            float a   = __shfl(ex, t);
            int  srcj = __shfl(sj, t);
            unsigned int p = ((const unsigned int*)(z16 + (size_t)srcj * DD))[lane];
            acc.x = fmaf(a, bf2f((unsigned short)(p & 0xFFFFu)), acc.x);
            acc.y = fmaf(a, bf2f((unsigned short)(p >> 16)),     acc.y);
        }
    }
#pragma unroll
    for (int o = 32; o >= 1; o >>= 1) ssum += __shfl_xor(ssum, o);
    float inv = 1.0f / ssum;
    orow[lane] = make_float2(acc.x * inv, acc.y * inv);
}

extern "C" void kernel_launch(void* const* d_in, const int* in_sizes, int n_in,
                              void* d_out, int out_size, void* d_ws, size_t ws_size,
                              hipStream_t stream) {
    const float* h    = (const float*)d_in[0];
    const int*   src  = (const int*)d_in[1];
    const int*   dst  = (const int*)d_in[2];
    const float* W    = (const float*)d_in[3];
    const float* attn = (const float*)d_in[4];
    const int N = in_sizes[0] / DD;
    const int E = in_sizes[1];
    float* out = (float*)d_out;

    // workspace layout
    unsigned short* z16 = (unsigned short*)d_ws;         // N*128 bf16 (12.8 MB)
    float* ll = (float*)(z16 + (size_t)N * DD);          // N floats
    float* lr = ll + N;                                   // N floats
    int* start = (int*)(lr + N);                          // N+1 ints

    k_gemm_mfma<<<(N + 127) / 128, 256, 0, stream>>>(h, W, attn, z16, ll, lr, N);
    k_starts<<<(N + 1 + 255) / 256, 256, 0, stream>>>(dst, E, N, start);
    k_edge<<<(N + 3) / 4, 256, 0, stream>>>(z16, src, start, ll, lr, out, N);
}

// Round 3
// 77.949 us; speedup vs baseline: 2.1811x; 1.2466x over previous
//
#include <hip/hip_runtime.h>
#include <hip/hip_bf16.h>

#define DD 128
#define NEGS 0.01f

typedef float  f32x4 __attribute__((ext_vector_type(4)));
typedef __bf16 bf16x8 __attribute__((ext_vector_type(8)));
typedef unsigned short us8 __attribute__((ext_vector_type(8)));

__device__ __forceinline__ unsigned short f2bf(float f) {
    unsigned int u = __builtin_bit_cast(unsigned int, f);
    u += 0x7FFFu + ((u >> 16) & 1u);          // RNE (no NaN inputs here)
    return (unsigned short)(u >> 16);
}
__device__ __forceinline__ float bflo(unsigned int u) {   // low bf16 of dword
    return __builtin_bit_cast(float, u << 16);
}
__device__ __forceinline__ float bfhi(unsigned int u) {   // high bf16 of dword
    return __builtin_bit_cast(float, u & 0xFFFF0000u);
}

// ---------------- prep: W (128x128 fp32) -> bf16 ----------------
__global__ __launch_bounds__(256)
void k_prep(const float* __restrict__ W, unsigned short* __restrict__ W16)
{
    int i = blockIdx.x * 256 + threadIdx.x;   // 16384 threads
    W16[i] = f2bf(W[i]);
}

// ---------- fused GEMM + logits: z16 = bf16(h @ W^T), ll/lr = z @ a ------
// One wave computes 32 rows of z (2 row-tiles x 8 col-tiles, K=128).
// C/D mapping: col = lane&15, row = (lane>>4)*4 + reg   [m89 verified]
__global__ __launch_bounds__(256)
void k_gemm_mfma(const float* __restrict__ h, const unsigned short* __restrict__ W16,
                 const float* __restrict__ attn,
                 unsigned short* __restrict__ z16,
                 float* __restrict__ ll, float* __restrict__ lr, int N)
{
    const int lane = threadIdx.x & 63;
    const int gw   = (blockIdx.x * 256 + threadIdx.x) >> 6;
    const int i0   = gw * 32;
    if (i0 >= N) return;
    const int hl = lane & 15;
    const int g  = lane >> 4;
    const int ko = g * 8;

    int r0 = i0 + hl;       if (r0 > N - 1) r0 = N - 1;   // clamp loads; stores guarded
    int r1 = i0 + 16 + hl;  if (r1 > N - 1) r1 = N - 1;

    f32x4 acc[2][8];
#pragma unroll
    for (int rt = 0; rt < 2; ++rt)
#pragma unroll
        for (int jt = 0; jt < 8; ++jt) acc[rt][jt] = f32x4{0.f, 0.f, 0.f, 0.f};

#pragma unroll
    for (int kk = 0; kk < DD; kk += 32) {
        const float* pa0 = h + (size_t)r0 * DD + kk + ko;
        const float* pa1 = h + (size_t)r1 * DD + kk + ko;
        float4 v0a = *(const float4*)pa0, v0b = *(const float4*)(pa0 + 4);
        float4 v1a = *(const float4*)pa1, v1b = *(const float4*)(pa1 + 4);
        us8 ua0 = { f2bf(v0a.x), f2bf(v0a.y), f2bf(v0a.z), f2bf(v0a.w),
                    f2bf(v0b.x), f2bf(v0b.y), f2bf(v0b.z), f2bf(v0b.w) };
        us8 ua1 = { f2bf(v1a.x), f2bf(v1a.y), f2bf(v1a.z), f2bf(v1a.w),
                    f2bf(v1b.x), f2bf(v1b.y), f2bf(v1b.z), f2bf(v1b.w) };
        bf16x8 a0 = __builtin_bit_cast(bf16x8, ua0);
        bf16x8 a1 = __builtin_bit_cast(bf16x8, ua1);
#pragma unroll
        for (int jt = 0; jt < 8; ++jt) {
            us8 ub = *(const us8*)(W16 + (size_t)(jt * 16 + hl) * DD + kk + ko);
            bf16x8 b = __builtin_bit_cast(bf16x8, ub);
            acc[0][jt] = __builtin_amdgcn_mfma_f32_16x16x32_bf16(a0, b, acc[0][jt], 0, 0, 0);
            acc[1][jt] = __builtin_amdgcn_mfma_f32_16x16x32_bf16(a1, b, acc[1][jt], 0, 0, 0);
        }
    }

    // epilogue: store z16 + fused logits
    float aLc[8], aRc[8];
#pragma unroll
    for (int jt = 0; jt < 8; ++jt) {
        aLc[jt] = attn[jt * 16 + hl];
        aRc[jt] = attn[DD + jt * 16 + hl];
    }
#pragma unroll
    for (int rt = 0; rt < 2; ++rt) {
#pragma unroll
        for (int reg = 0; reg < 4; ++reg) {
            const int row = i0 + rt * 16 + g * 4 + reg;
            float pl = 0.f, pr = 0.f;
#pragma unroll
            for (int jt = 0; jt < 8; ++jt) {
                float v = acc[rt][jt][reg];
                pl = fmaf(v, aLc[jt], pl);
                pr = fmaf(v, aRc[jt], pr);
            }
#pragma unroll
            for (int o = 8; o >= 1; o >>= 1) {   // reduce across 16 cols
                pl += __shfl_xor(pl, o);
                pr += __shfl_xor(pr, o);
            }
            if (row < N) {
                if (hl == 0) { ll[row] = pl; lr[row] = pr; }
                unsigned short* zr = z16 + (size_t)row * DD;
#pragma unroll
                for (int jt = 0; jt < 8; ++jt)
                    zr[jt * 16 + hl] = f2bf(acc[rt][jt][reg]);
            }
        }
    }
}

// ---------------- segment starts: start[n] = lower_bound(dst, n) ----------
__global__ __launch_bounds__(256)
void k_starts(const int* __restrict__ dst, int E, int N, int* __restrict__ start)
{
    int n = blockIdx.x * 256 + threadIdx.x;
    if (n > N) return;
    int lo = 0, hi = E;
    while (lo < hi) {
        int mid = (lo + hi) >> 1;
        if (dst[mid] < n) lo = mid + 1; else hi = mid;
    }
    start[n] = lo;
}

// ---------------- edge weights: w[j] = exp(leaky(ll[src]+lr[dst])) --------
// No max-subtraction: logits are O(10), exp() fp32-safe, softmax shift-invariant.
__global__ __launch_bounds__(256)
void k_ew(const int* __restrict__ src, const int* __restrict__ dst,
          const float* __restrict__ ll, const float* __restrict__ lr,
          float* __restrict__ w, int E)
{
    int j = blockIdx.x * 256 + threadIdx.x;
    if (j >= E) return;
    float v = ll[src[j]] + lr[dst[j]];
    float e = (v >= 0.f) ? v : NEGS * v;
    w[j] = __expf(e);
}

// ---------------- output: out[n] = (sum_j w_j * z[src_j]) / (sum_j w_j) ---
// wave = node; 4 quarter-waves process 4 edges/iter; 16 lanes x 16B cover a row.
__global__ __launch_bounds__(256)
void k_out(const unsigned short* __restrict__ z16, const int* __restrict__ src,
           const float* __restrict__ w, const int* __restrict__ start,
           float* __restrict__ out, int N)
{
    int wid  = (blockIdx.x * 256 + threadIdx.x) >> 6;
    int lane = threadIdx.x & 63;
    if (wid >= N) return;
    const int s0 = start[wid], s1 = start[wid + 1];
    const int q = lane >> 4;      // quarter 0..3 -> edge t = base + q
    const int c = lane & 15;      // col block: cols 8c .. 8c+7

    float acc[8];
#pragma unroll
    for (int k = 0; k < 8; ++k) acc[k] = 0.f;
    float ssum = 0.f;

    for (int base = s0; base < s1; base += 4) {
        int t = base + q;
        float wq = 0.f; int sj = 0;
        if (t < s1) { wq = w[t]; sj = src[t]; }
        ssum += wq;
        uint4 zv = *(const uint4*)(z16 + (size_t)sj * DD + c * 8);
        acc[0] = fmaf(wq, bflo(zv.x), acc[0]);
        acc[1] = fmaf(wq, bfhi(zv.x), acc[1]);
        acc[2] = fmaf(wq, bflo(zv.y), acc[2]);
        acc[3] = fmaf(wq, bfhi(zv.y), acc[3]);
        acc[4] = fmaf(wq, bflo(zv.z), acc[4]);
        acc[5] = fmaf(wq, bfhi(zv.z), acc[5]);
        acc[6] = fmaf(wq, bflo(zv.w), acc[6]);
        acc[7] = fmaf(wq, bfhi(zv.w), acc[7]);
    }
    // combine the 4 quarters (lanes {l, l^16, l^32, l^48} share a col block)
#pragma unroll
    for (int k = 0; k < 8; ++k) {
        acc[k] += __shfl_xor(acc[k], 16);
        acc[k] += __shfl_xor(acc[k], 32);
    }
    ssum += __shfl_xor(ssum, 16);
    ssum += __shfl_xor(ssum, 32);
    float inv = (s1 > s0) ? 1.0f / ssum : 0.f;   // empty segment -> zeros

    float* orow = out + (size_t)wid * DD + c * 8;
    if (q == 0) {
        ((float4*)orow)[0] = make_float4(acc[0]*inv, acc[1]*inv, acc[2]*inv, acc[3]*inv);
    } else if (q == 1) {
        ((float4*)orow)[1] = make_float4(acc[4]*inv, acc[5]*inv, acc[6]*inv, acc[7]*inv);
    }
}

extern "C" void kernel_launch(void* const* d_in, const int* in_sizes, int n_in,
                              void* d_out, int out_size, void* d_ws, size_t ws_size,
                              hipStream_t stream) {
    const float* h    = (const float*)d_in[0];
    const int*   src  = (const int*)d_in[1];
    const int*   dst  = (const int*)d_in[2];
    const float* W    = (const float*)d_in[3];
    const float* attn = (const float*)d_in[4];
    const int N = in_sizes[0] / DD;
    const int E = in_sizes[1];
    float* out = (float*)d_out;

    // workspace layout
    unsigned short* z16 = (unsigned short*)d_ws;          // N*128 bf16 (12.8 MB)
    float* ll  = (float*)(z16 + (size_t)N * DD);          // N
    float* lr  = ll + N;                                  // N
    float* w   = lr + N;                                  // E  (3.2 MB)
    int* start = (int*)(w + E);                           // N+1
    unsigned short* W16 = (unsigned short*)(start + N + 1); // 16384

    k_prep<<<64, 256, 0, stream>>>(W, W16);
    k_gemm_mfma<<<(N + 127) / 128, 256, 0, stream>>>(h, W16, attn, z16, ll, lr, N);
    k_starts<<<(N + 1 + 255) / 256, 256, 0, stream>>>(dst, E, N, start);
    k_ew<<<(E + 255) / 256, 256, 0, stream>>>(src, dst, ll, lr, w, E);
    k_out<<<(N + 3) / 4, 256, 0, stream>>>(z16, src, w, start, out, N);
}

// Round 4
// 75.188 us; speedup vs baseline: 2.2612x; 1.0367x over previous
//
#include <hip/hip_runtime.h>
#include <hip/hip_bf16.h>

#define DD 128
#define NEGS 0.01f

typedef float  f32x4 __attribute__((ext_vector_type(4)));
typedef __bf16 bf16x8 __attribute__((ext_vector_type(8)));
typedef unsigned short us8 __attribute__((ext_vector_type(8)));

__device__ __forceinline__ unsigned short f2bf(float f) {
    unsigned int u = __builtin_bit_cast(unsigned int, f);
    u += 0x7FFFu + ((u >> 16) & 1u);          // RNE (no NaN inputs here)
    return (unsigned short)(u >> 16);
}
__device__ __forceinline__ float bflo(unsigned int u) {
    return __builtin_bit_cast(float, u << 16);
}
__device__ __forceinline__ float bfhi(unsigned int u) {
    return __builtin_bit_cast(float, u & 0xFFFF0000u);
}

// -------- aux: blocks [0,64): W fp32->bf16 ; blocks [64,..): segment starts --
__global__ __launch_bounds__(256)
void k_aux(const float* __restrict__ W, unsigned short* __restrict__ W16,
           const int* __restrict__ dst, int E, int N, int* __restrict__ start)
{
    int b = blockIdx.x;
    if (b < 64) {
        int i = b * 256 + threadIdx.x;
        W16[i] = f2bf(W[i]);
    } else {
        int n = (b - 64) * 256 + threadIdx.x;
        if (n > N) return;
        int lo = 0, hi = E;
        while (lo < hi) {
            int mid = (lo + hi) >> 1;
            if (dst[mid] < n) lo = mid + 1; else hi = mid;
        }
        start[n] = lo;
    }
}

// ---------- fused GEMM + logits: z16 = bf16(h @ W^T), ll/lr = z @ a --------
// One wave computes 16 rows of z (1 row-tile x 8 col-tiles, K=128).
// 16 rows/wave (not 32): acc=32 VGPR -> more waves/SIMD; grid 2x -> latency hiding.
// C/D mapping: col = lane&15, row = (lane>>4)*4 + reg   [m89 verified]
__global__ __launch_bounds__(256)
void k_gemm_mfma(const float* __restrict__ h, const unsigned short* __restrict__ W16,
                 const float* __restrict__ attn,
                 unsigned short* __restrict__ z16,
                 float* __restrict__ ll, float* __restrict__ lr, int N)
{
    const int lane = threadIdx.x & 63;
    const int gw   = (blockIdx.x * 256 + threadIdx.x) >> 6;
    const int i0   = gw * 16;
    if (i0 >= N) return;
    const int hl = lane & 15;
    const int g  = lane >> 4;
    const int ko = g * 8;

    int r0 = i0 + hl; if (r0 > N - 1) r0 = N - 1;   // clamp loads; stores guarded

    f32x4 acc[8];
#pragma unroll
    for (int jt = 0; jt < 8; ++jt) acc[jt] = f32x4{0.f, 0.f, 0.f, 0.f};

#pragma unroll
    for (int kk = 0; kk < DD; kk += 32) {
        const float* pa = h + (size_t)r0 * DD + kk + ko;
        float4 va = *(const float4*)pa, vb = *(const float4*)(pa + 4);
        us8 ua = { f2bf(va.x), f2bf(va.y), f2bf(va.z), f2bf(va.w),
                   f2bf(vb.x), f2bf(vb.y), f2bf(vb.z), f2bf(vb.w) };
        bf16x8 a = __builtin_bit_cast(bf16x8, ua);
#pragma unroll
        for (int jt = 0; jt < 8; ++jt) {
            us8 ub = *(const us8*)(W16 + (size_t)(jt * 16 + hl) * DD + kk + ko);
            bf16x8 b = __builtin_bit_cast(bf16x8, ub);
            acc[jt] = __builtin_amdgcn_mfma_f32_16x16x32_bf16(a, b, acc[jt], 0, 0, 0);
        }
    }

    // epilogue: store z16 + fused logits
    float aLc[8], aRc[8];
#pragma unroll
    for (int jt = 0; jt < 8; ++jt) {
        aLc[jt] = attn[jt * 16 + hl];
        aRc[jt] = attn[DD + jt * 16 + hl];
    }
#pragma unroll
    for (int reg = 0; reg < 4; ++reg) {
        const int row = i0 + g * 4 + reg;
        float pl = 0.f, pr = 0.f;
#pragma unroll
        for (int jt = 0; jt < 8; ++jt) {
            float v = acc[jt][reg];
            pl = fmaf(v, aLc[jt], pl);
            pr = fmaf(v, aRc[jt], pr);
        }
#pragma unroll
        for (int o = 8; o >= 1; o >>= 1) {   // reduce across 16 cols
            pl += __shfl_xor(pl, o);
            pr += __shfl_xor(pr, o);
        }
        if (row < N) {
            if (hl == 0) { ll[row] = pl; lr[row] = pr; }
            unsigned short* zr = z16 + (size_t)row * DD;
#pragma unroll
            for (int jt = 0; jt < 8; ++jt)
                zr[jt * 16 + hl] = f2bf(acc[jt][reg]);
        }
    }
}

// ---------------- edge weights: w[j] = exp(leaky(ll[src]+lr[dst])) --------
// No max-subtraction: logits are O(10), exp() fp32-safe, softmax shift-invariant.
__global__ __launch_bounds__(256)
void k_ew(const int* __restrict__ src, const int* __restrict__ dst,
          const float* __restrict__ ll, const float* __restrict__ lr,
          float* __restrict__ w, int E)
{
    int j = blockIdx.x * 256 + threadIdx.x;
    if (j >= E) return;
    float v = ll[src[j]] + lr[dst[j]];
    float e = (v >= 0.f) ? v : NEGS * v;
    w[j] = __expf(e);
}

// ---------------- output: out[n] = (sum_j w_j * z[src_j]) / (sum_j w_j) ---
// wave = node; 4 quarter-waves, 2 edges each per iter (8 edges/iter);
// unconditional clamped loads so the compiler can pipeline them.
__global__ __launch_bounds__(256)
void k_out(const unsigned short* __restrict__ z16, const int* __restrict__ src,
           const float* __restrict__ w, const int* __restrict__ start,
           float* __restrict__ out, int N)
{
    int wid  = (blockIdx.x * 256 + threadIdx.x) >> 6;
    int lane = threadIdx.x & 63;
    if (wid >= N) return;
    const int s0 = start[wid], s1 = start[wid + 1];
    const int q = lane >> 4;      // quarter 0..3
    const int c = lane & 15;      // col block: cols 8c .. 8c+7

    float acc[8];
#pragma unroll
    for (int k = 0; k < 8; ++k) acc[k] = 0.f;
    float ssum = 0.f;
    const int last = s1 - 1;

    for (int base = s0; base < s1; base += 8) {
        int t0 = base + q;
        int t1 = t0 + 4;
        int tc0 = (t0 <= last) ? t0 : last;
        int tc1 = (t1 <= last) ? t1 : last;
        float w0 = w[tc0];
        float w1 = w[tc1];
        int  sj0 = src[tc0];
        int  sj1 = src[tc1];
        if (t0 > last) w0 = 0.f;
        if (t1 > last) w1 = 0.f;
        uint4 z0 = *(const uint4*)(z16 + (size_t)sj0 * DD + c * 8);
        uint4 z1 = *(const uint4*)(z16 + (size_t)sj1 * DD + c * 8);
        ssum += w0 + w1;
        acc[0] = fmaf(w0, bflo(z0.x), fmaf(w1, bflo(z1.x), acc[0]));
        acc[1] = fmaf(w0, bfhi(z0.x), fmaf(w1, bfhi(z1.x), acc[1]));
        acc[2] = fmaf(w0, bflo(z0.y), fmaf(w1, bflo(z1.y), acc[2]));
        acc[3] = fmaf(w0, bfhi(z0.y), fmaf(w1, bfhi(z1.y), acc[3]));
        acc[4] = fmaf(w0, bflo(z0.z), fmaf(w1, bflo(z1.z), acc[4]));
        acc[5] = fmaf(w0, bfhi(z0.z), fmaf(w1, bfhi(z1.z), acc[5]));
        acc[6] = fmaf(w0, bflo(z0.w), fmaf(w1, bflo(z1.w), acc[6]));
        acc[7] = fmaf(w0, bfhi(z0.w), fmaf(w1, bfhi(z1.w), acc[7]));
    }
    // combine the 4 quarters (lanes {l, l^16, l^32, l^48} share a col block)
#pragma unroll
    for (int k = 0; k < 8; ++k) {
        acc[k] += __shfl_xor(acc[k], 16);
        acc[k] += __shfl_xor(acc[k], 32);
    }
    ssum += __shfl_xor(ssum, 16);
    ssum += __shfl_xor(ssum, 32);
    float inv = (s1 > s0) ? 1.0f / ssum : 0.f;   // empty segment -> zeros

    float* orow = out + (size_t)wid * DD + c * 8;
    if (q == 0) {
        ((float4*)orow)[0] = make_float4(acc[0]*inv, acc[1]*inv, acc[2]*inv, acc[3]*inv);
    } else if (q == 1) {
        ((float4*)orow)[1] = make_float4(acc[4]*inv, acc[5]*inv, acc[6]*inv, acc[7]*inv);
    }
}

extern "C" void kernel_launch(void* const* d_in, const int* in_sizes, int n_in,
                              void* d_out, int out_size, void* d_ws, size_t ws_size,
                              hipStream_t stream) {
    const float* h    = (const float*)d_in[0];
    const int*   src  = (const int*)d_in[1];
    const int*   dst  = (const int*)d_in[2];
    const float* W    = (const float*)d_in[3];
    const float* attn = (const float*)d_in[4];
    const int N = in_sizes[0] / DD;
    const int E = in_sizes[1];
    float* out = (float*)d_out;

    // workspace layout
    unsigned short* z16 = (unsigned short*)d_ws;          // N*128 bf16 (12.8 MB)
    float* ll  = (float*)(z16 + (size_t)N * DD);          // N
    float* lr  = ll + N;                                  // N
    float* w   = lr + N;                                  // E (3.2 MB)
    int* start = (int*)(w + E);                           // N+1
    unsigned short* W16 = (unsigned short*)(start + N + 1); // 16384

    k_aux<<<64 + (N + 1 + 255) / 256, 256, 0, stream>>>(W, W16, dst, E, N, start);
    k_gemm_mfma<<<(N + 63) / 64, 256, 0, stream>>>(h, W16, attn, z16, ll, lr, N);
    k_ew<<<(E + 255) / 256, 256, 0, stream>>>(src, dst, ll, lr, w, E);
    k_out<<<(N + 3) / 4, 256, 0, stream>>>(z16, src, w, start, out, N);
}